// Round 10
// baseline (384.384 us; speedup 1.0000x reference)
//
#include <hip/hip_runtime.h>
#include <hip/hip_bf16.h>
#include <math.h>

#define N_NODES  50000
#define N_EDGES  800000
#define HIDDEN   256
#define HEADS    8
#define HEAD_DIM 32
#define MAXDEG   64
#define KVSTRIDE 512               // K row | V row interleaved per node
#define QKV_NB   2346              // 391 row-tiles x 6 col-tiles
#define O_NB     782               // 391 row-tiles x 2 col-tiles

using short8 = __attribute__((ext_vector_type(8))) short;
using f32x4  = __attribute__((ext_vector_type(4))) float;

__device__ __forceinline__ float b2f(unsigned short u) {
  union { unsigned int i; float f; } v; v.i = ((unsigned int)u) << 16; return v.f;
}
__device__ __forceinline__ unsigned short f2b(float f) {
  union { float f; unsigned int i; } v; v.f = f;
  unsigned int r = v.i + 0x7FFF + ((v.i >> 16) & 1);   // round-to-nearest-even
  return (unsigned short)(r >> 16);
}
// unpack a dword holding 2 bf16 into 2 floats (1 shl + 1 and)
__device__ __forceinline__ void unpack2(unsigned int d, float& lo, float& hi) {
  union { unsigned int i; float f; } a, b;
  a.i = d << 16; b.i = d & 0xFFFF0000u;
  lo = a.f; hi = b.f;
}

// Bijective XCD-chunked block swizzle (m204 variant).
template<int NB, int NCT>
__device__ __forceinline__ void xcd_map(int b, int& rt, int& ct) {
  constexpr int q = NB / 8, r = NB % 8;
  const int xcd = b & 7, j = b >> 3;
  const int id = (xcd < r ? xcd * (q + 1) : r * (q + 1) + (xcd - r) * q) + j;
  rt = id / NCT; ct = id - rt * NCT;
}

// ---- init: block 0 = dtype detection; other blocks zero the cursor array.
// flags[0]=1 if float tensors are fp32; flags[1]=1 if idx int64
__global__ __launch_bounds__(256) void init(const unsigned short* __restrict__ h16,
                                            const int* __restrict__ rowraw,
                                            int* __restrict__ flags,
                                            int* __restrict__ cur) {
  const int tid = threadIdx.x;
  if (blockIdx.x == 0) {
    __shared__ int nan_cnt, hi_viol, lo_pos;
    if (tid == 0) { nan_cnt = 0; hi_viol = 0; lo_pos = 0; }
    __syncthreads();
    int local = 0;
    for (int i = tid; i < 16384; i += 256)
      if ((h16[i] & 0x7F80) == 0x7F80) local++;   // bf16 NaN/Inf pattern: ~1/256 if fp32
    if (local) atomicAdd(&nan_cnt, local);
    int viol = 0, pos = 0;
    for (int e = tid; e < 512; e += 256) {
      if (rowraw[2 * e + 1] != 0) viol++;
      if (rowraw[2 * e] > 0) pos++;
    }
    if (viol) atomicAdd(&hi_viol, viol);
    if (pos) atomicAdd(&lo_pos, pos);
    __syncthreads();
    if (tid == 0) {
      flags[0] = (nan_cnt >= 4) ? 1 : 0;
      flags[1] = (hi_viol == 0 && lo_pos > 0) ? 1 : 0;
    }
  } else {
    const int i = (blockIdx.x - 1) * 256 + tid;       // 63*256 = 16128 >= 12500
    if (i < N_NODES / 4) ((int4*)cur)[i] = make_int4(0, 0, 0, 0);
  }
}

// Weights + biases pointer pack.
// Wq/Wk/Wv: ROW-permuted (head-major outputs); Wo: K-DIM permuted.
struct WPtrs {
  const void* srcW[4]; unsigned short* dstW[4];
  const void* srcB[4]; unsigned short* dstB[4];
};

// ---- prep: fused h-conversion + weight/bias permute-convert + bucket build.
// Block ranges: [0,6400) h->bf16; [6400,6850) weights; [6850,9975) buckets.
__global__ __launch_bounds__(256) void prep(
    const void* __restrict__ hsrc, unsigned short* __restrict__ Hc, WPtrs p,
    const int* __restrict__ rowraw, const int* __restrict__ colraw,
    const int* __restrict__ flags, int* __restrict__ cursor,
    unsigned short* __restrict__ bucket)
{
  const int fp32 = flags[0];
  const int bid = blockIdx.x, tid = threadIdx.x;

  if (bid < 6400) {                        // canonicalize h -> bf16, vec4
    const int n4 = N_NODES * HIDDEN / 4;
    for (int i = bid * 256 + tid; i < n4; i += 6400 * 256) {
      if (fp32) {
        const float4 v = ((const float4*)hsrc)[i];
        ushort4 o; o.x = f2b(v.x); o.y = f2b(v.y); o.z = f2b(v.z); o.w = f2b(v.w);
        ((ushort4*)Hc)[i] = o;
      } else {
        ((ushort4*)Hc)[i] = ((const ushort4*)hsrc)[i];
      }
    }
  } else if (bid < 6850) {                 // weights + biases
    const int idx = (bid - 6400) * 256 + tid;
    if (idx < 49152) {                     // Wq,Wk,Wv: vec4 along k, row-permuted
      const int m = idx >> 14, r = idx & 16383;
      const int g = r >> 6, kc = r & 63;
      const int f = ((g & 31) << 3) | (g >> 5);   // source row
      const int s = f * 64 + kc;
      if (fp32) {
        const float4 v = ((const float4*)p.srcW[m])[s];
        ushort4 o; o.x = f2b(v.x); o.y = f2b(v.y); o.z = f2b(v.z); o.w = f2b(v.w);
        ((ushort4*)p.dstW[m])[g * 64 + kc] = o;
      } else {
        ((ushort4*)p.dstW[m])[g * 64 + kc] = ((const ushort4*)p.srcW[m])[s];
      }
    } else if (idx < 49152 + 65536) {      // Wo: scalar, permuted k index
      const int g = idx - 49152;
      const int f = g >> 8, kk = g & 255;
      const int s = f * 256 + (((kk & 31) << 3) | (kk >> 5));
      p.dstW[3][g] = fp32 ? f2b(((const float*)p.srcW[3])[s])
                          : ((const unsigned short*)p.srcW[3])[s];
    } else if (idx < 49152 + 65536 + 256) {  // biases
      const int t = idx - 49152 - 65536;
      const int m = t >> 6, r = t & 63;
      if (m < 3) {
        ushort4 o;
        #pragma unroll
        for (int x = 0; x < 4; ++x) {
          const int g = r * 4 + x;
          const int f = ((g & 31) << 3) | (g >> 5);
          ((unsigned short*)&o)[x] = fp32 ? f2b(((const float*)p.srcB[m])[f])
                                          : ((const unsigned short*)p.srcB[m])[f];
        }
        ((ushort4*)p.dstB[m])[r] = o;
      } else {
        if (fp32) {
          const float4 v = ((const float4*)p.srcB[3])[r];
          ushort4 o; o.x = f2b(v.x); o.y = f2b(v.y); o.z = f2b(v.z); o.w = f2b(v.w);
          ((ushort4*)p.dstB[3])[r] = o;
        } else {
          ((ushort4*)p.dstB[3])[r] = ((const ushort4*)p.srcB[3])[r];
        }
      }
    }
  } else {                                 // bucket build; ushort cols (N<65536)
    const int e = (bid - 6850) * 256 + tid;
    if (e < N_EDGES) {
      const int i64 = flags[1];
      const int r = i64 ? rowraw[2 * e] : rowraw[e];
      const int c = i64 ? colraw[2 * e] : colraw[e];
      const int pos = atomicAdd(&cursor[r], 1);
      if (pos < MAXDEG) bucket[r * MAXDEG + pos] = (unsigned short)c;
    }
  }
}

// ---- m97-style staging: 128x64 bf16 tile -> LDS [128][64], XOR-swizzled.
#if defined(__has_builtin)
#if __has_builtin(__builtin_amdgcn_global_load_lds)
#define HAVE_GLL 1
#endif
#endif
__device__ __forceinline__ void stage_tile(
    const unsigned short* __restrict__ src, int row_base, int row_max,
    int kb, unsigned short* lds, int wave, int lane)
{
  #pragma unroll
  for (int c = 0; c < 4; ++c) {
    const int chunk = wave * 4 + c;                    // 0..15 (wave-uniform)
    const int r = chunk * 8 + (lane >> 3);             // LDS row 0..127
    int gr = row_base + r; if (gr > row_max) gr = row_max;
    const int scb = (lane & 7) ^ ((lane >> 3) & 7);    // swizzled source col-block
    const unsigned short* gp = src + (size_t)gr * HIDDEN + kb * 64 + scb * 8;
#ifdef HAVE_GLL
    __builtin_amdgcn_global_load_lds(
        (const __attribute__((address_space(1))) void*)gp,
        (__attribute__((address_space(3))) void*)(lds + chunk * 512),
        16, 0, 0);
#else
    *(short8*)(lds + chunk * 512 + lane * 8) = *(const short8*)gp;
#endif
  }
}

// generic 128x128 block-tile MFMA core, DOUBLE-BUFFERED (T3-minimum 2-phase).
#define GEMM_CORE(A_SRC, AROWB, AROWM, B_SRC, BROWB, BROWM)                          \
  __shared__ unsigned short sA[2][8192], sB[2][8192];                                \
  const int wave = threadIdx.x >> 6, lane = threadIdx.x & 63;                        \
  const int lrow = lane & 15, quad = lane >> 4;                                      \
  const int wr0 = (wave & 1) * 64, wc0 = (wave >> 1) * 64;                           \
  f32x4 acc[4][4];                                                                   \
  _Pragma("unroll")                                                                  \
  for (int i = 0; i < 4; ++i)                                                        \
    _Pragma("unroll")                                                                \
    for (int j = 0; j < 4; ++j) acc[i][j] = (f32x4){0.f, 0.f, 0.f, 0.f};            \
  stage_tile(A_SRC, AROWB, AROWM, 0, sA[0], wave, lane);                             \
  stage_tile(B_SRC, BROWB, BROWM, 0, sB[0], wave, lane);                             \
  _Pragma("unroll")                                                                  \
  for (int kb = 0; kb < 4; ++kb) {                                                   \
    __syncthreads();                        /* buf[kb&1] ready; prior reads done */  \
    if (kb < 3) {                                                                    \
      stage_tile(A_SRC, AROWB, AROWM, kb + 1, sA[(kb + 1) & 1], wave, lane);         \
      stage_tile(B_SRC, BROWB, BROWM, kb + 1, sB[(kb + 1) & 1], wave, lane);         \
    }                                                                                \
    const unsigned short* pA = sA[kb & 1];                                           \
    const unsigned short* pB = sB[kb & 1];                                           \
    _Pragma("unroll")                                                                \
    for (int kk = 0; kk < 2; ++kk) {                                                 \
      short8 af[4], bf[4];                                                           \
      _Pragma("unroll")                                                              \
      for (int i = 0; i < 4; ++i) {                                                  \
        const int rr = wr0 + i * 16 + lrow;                                          \
        af[i] = *(const short8*)(pA + rr * 64 + (((kk * 4 + quad) ^ (lrow & 7)) * 8));\
      }                                                                              \
      _Pragma("unroll")                                                              \
      for (int j = 0; j < 4; ++j) {                                                  \
        const int rr = wc0 + j * 16 + lrow;                                          \
        bf[j] = *(const short8*)(pB + rr * 64 + (((kk * 4 + quad) ^ (lrow & 7)) * 8));\
      }                                                                              \
      _Pragma("unroll")                                                              \
      for (int i = 0; i < 4; ++i)                                                    \
        _Pragma("unroll")                                                            \
        for (int j = 0; j < 4; ++j)                                                  \
          acc[i][j] = __builtin_amdgcn_mfma_f32_16x16x32_bf16(af[i], bf[j], acc[i][j], 0, 0, 0); \
    }                                                                                \
  }

// QKV fused: C[50000, 768] = Hc @ WQKV^T (+bias)(*scale for Q cols).
__global__ __launch_bounds__(256) void gemm_qkv(
    const unsigned short* __restrict__ X, const unsigned short* __restrict__ WQKV,
    const unsigned short* __restrict__ biasAll,
    unsigned short* __restrict__ Qt, unsigned short* __restrict__ KV, float qscale)
{
  int rt, ct; xcd_map<QKV_NB, 6>(blockIdx.x, rt, ct);
  const int row0 = rt * 128;
  const int col0 = ct * 128;
  GEMM_CORE(X, row0, N_NODES - 1, WQKV, col0, 767)

  #pragma unroll
  for (int j = 0; j < 4; ++j) {
    const int gcol = col0 + wc0 + j * 16;          // multiple of 16
    const int m = gcol >> 8;
    const int f = (gcol & 255) + lrow;
    const float scale = (m == 0) ? qscale : 1.0f;
    const float bv = b2f(biasAll[gcol + lrow]);
    unsigned short* bp = (m == 0) ? Qt : (KV + ((m == 2) ? 256 : 0));
    const int ldv = (m == 0) ? 256 : KVSTRIDE;
    #pragma unroll
    for (int i = 0; i < 4; ++i) {
      #pragma unroll
      for (int r = 0; r < 4; ++r) {
        const int row = row0 + wr0 + i * 16 + quad * 4 + r;
        if (row < N_NODES)
          bp[(size_t)row * ldv + f] = f2b((acc[i][j][r] + bv) * scale);
      }
    }
  }
}

// O-projection: C[50000, 256] = pre @ WoP^T + bo; out fp32/bf16 per flags[0].
__global__ __launch_bounds__(256) void gemm_o(
    const unsigned short* __restrict__ X, const unsigned short* __restrict__ W,
    const unsigned short* __restrict__ bias, void* __restrict__ Yv,
    const int* __restrict__ flags)
{
  int rt, ct; xcd_map<O_NB, 2>(blockIdx.x, rt, ct);
  const int row0 = rt * 128;
  const int col0 = ct * 128;
  const int out_fp32 = flags[0];
  GEMM_CORE(X, row0, N_NODES - 1, W, col0, 255)

  #pragma unroll
  for (int j = 0; j < 4; ++j) {
    const int col = col0 + wc0 + j * 16 + lrow;
    const float bv = b2f(bias[col]);
    #pragma unroll
    for (int i = 0; i < 4; ++i) {
      #pragma unroll
      for (int r = 0; r < 4; ++r) {
        const int row = row0 + wr0 + i * 16 + quad * 4 + r;
        if (row < N_NODES) {
          const float y = acc[i][j][r] + bv;
          if (out_fp32) ((float*)Yv)[(size_t)row * HIDDEN + col] = y;
          else ((unsigned short*)Yv)[(size_t)row * HIDDEN + col] = f2b(y);
        }
      }
    }
  }
}

// Fused SDDMM + exp + SPMM — frozen at the gather-path roofline.
// DIAGNOSTIC SPLIT this round: launched twice over node halves (~58 µs
// each) so the top-5 dispatch table can reveal the hidden non-attn
// kernels (everything <115 µs was invisible behind full-size attn).
__global__ __launch_bounds__(256) void attn_fused(
    const unsigned short* __restrict__ Qt, const unsigned short* __restrict__ KV,
    const int* __restrict__ cursor, const unsigned short* __restrict__ bucket,
    unsigned short* __restrict__ pre, int node_base)
{
  const int node = node_base + blockIdx.x * 4 + (threadIdx.x >> 6);
  if (node >= N_NODES) return;
  const int lane = threadIdx.x & 63;
  const int side = lane >> 5;          // which edge of the current pair
  const int sub  = lane & 31;          // owns cols [8*sub, 8*sub+8)
  const unsigned suboff = (unsigned)(sub * 8);
  int cnt = cursor[node]; if (cnt > MAXDEG) cnt = MAXDEG;

  // Q: 8 floats (scale already folded in by gemm_qkv); both halves read same row
  const uint4 qd = *(const uint4*)(Qt + (unsigned)node * HIDDEN + suboff);
  float q[8];
  unpack2(qd.x, q[0], q[1]); unpack2(qd.y, q[2], q[3]);
  unpack2(qd.z, q[4], q[5]); unpack2(qd.w, q[6], q[7]);

  float a[8] = {0.f, 0.f, 0.f, 0.f, 0.f, 0.f, 0.f, 0.f};
  float z = 0.f;

  if (cnt > 0) {
    const int last = cnt - 1;
    const unsigned short* brow = bucket + node * MAXDEG;
    // clamped per-lane edge index: any shuffle source yields a valid col
    const int myidx = (int)brow[lane <= last ? lane : last];
    const int nit = (cnt + 1) >> 1;

    auto compute = [&](const uint4& kk, const uint4& vv, int jj) {
      float kf[8];
      unpack2(kk.x, kf[0], kf[1]); unpack2(kk.y, kf[2], kf[3]);
      unpack2(kk.z, kf[4], kf[5]); unpack2(kk.w, kf[6], kf[7]);
      float s0 = q[0]*kf[0] + q[2]*kf[2] + q[4]*kf[4] + q[6]*kf[6];
      float s1 = q[1]*kf[1] + q[3]*kf[3] + q[5]*kf[5] + q[7]*kf[7];
      float d = s0 + s1;
      d += __shfl_xor(d, 1, 64);       // 4-lane (one head) reduce: 2 rounds
      d += __shfl_xor(d, 2, 64);
      float w = __expf(d);
      if (2 * jj + side > last) w = 0.f;   // mask odd tail / clamped dup
      z += w;
      float vf[8];
      unpack2(vv.x, vf[0], vf[1]); unpack2(vv.y, vf[2], vf[3]);
      unpack2(vv.z, vf[4], vf[5]); unpack2(vv.w, vf[6], vf[7]);
      #pragma unroll
      for (int x = 0; x < 8; ++x) a[x] = fmaf(w, vf[x], a[x]);
    };

    // ---- prologue: pairs 0 and 1 in flight (clamped idx safe, masked later)
    const int cA = __shfl(myidx, side, 64);
    const unsigned offA = ((unsigned)cA << 9) + suboff;
    uint4 kA = *(const uint4*)(KV + offA);
    uint4 vA = *(const uint4*)(KV + offA + 256u);

    const int cB = __shfl(myidx, 2 + side, 64);      // lane 2/3: always valid
    const unsigned offB = ((unsigned)cB << 9) + suboff;
    uint4 kB = *(const uint4*)(KV + offB);
    uint4 vB = *(const uint4*)(KV + offB + 256u);

    int slC = 4 + side;                              // pair-2 source lane
    int cC = __shfl(myidx, slC, 64);

    int j = 0;
    #pragma unroll 2
    for (; j + 2 < nit; ++j) {
      const unsigned offC = ((unsigned)cC << 9) + suboff;
      const uint4 kC = *(const uint4*)(KV + offC);
      const uint4 vC = *(const uint4*)(KV + offC + 256u);
      int sl = 2 * (j + 3) + side; if (sl > 63) sl = 63;
      cC = __shfl(myidx, sl, 64);
      compute(kA, vA, j);
      kA = kB; vA = vB; kB = kC; vB = vC;
    }
    compute(kA, vA, j);                 // pair nit-2 (or nit-1 if nit==1)
    if (j + 1 < nit) compute(kB, vB, j + 1);   // pair nit-1
  }

  // cross-half combine (once per node)
  #pragma unroll
  for (int x = 0; x < 8; ++x) a[x] += __shfl_xor(a[x], 32, 64);
  z += __shfl_xor(z, 32, 64);
  const float zi = (z > 0.f) ? (1.f / z) : 0.f;

  if (side == 0) {
    short8 ov;
    #pragma unroll
    for (int x = 0; x < 8; ++x) ov[x] = (short)f2b(a[x] * zi);
    *(short8*)(pre + (unsigned)node * HIDDEN + suboff) = ov;
  }
}

extern "C" void kernel_launch(void* const* d_in, const int* in_sizes, int n_in,
                              void* d_out, int out_size, void* d_ws, size_t ws_size,
                              hipStream_t stream) {
  const void* h_raw  = d_in[0];
  const int* row_raw = (const int*)d_in[1];
  const int* col_raw = (const int*)d_in[2];
  const void* Wq_raw = d_in[3]; const void* bq_raw = d_in[4];
  const void* Wk_raw = d_in[5]; const void* bk_raw = d_in[6];
  const void* Wv_raw = d_in[7]; const void* bv_raw = d_in[8];
  const void* Wo_raw = d_in[9]; const void* bo_raw = d_in[10];

  char* ws = (char*)d_ws;
  unsigned short* Qt   = (unsigned short*)(ws +          0);  // 25.6 MB
  unsigned short* KV   = (unsigned short*)(ws +  25600000);   // 51.2 MB interleaved K|V
  int*            cur  = (int*)           (ws +  76800000);   // 0.2 MB
  unsigned short* bkt  = (unsigned short*)(ws +  77000000);   // 6.4 MB (ushort cols)
  unsigned short* pre  = (unsigned short*)(ws +  89800000);   // 25.6 MB
  unsigned short* WqP  = (unsigned short*)(ws + 115400000);   // 4 x 128 KB, contiguous
  unsigned short* WkP  = WqP + 65536;                         //  -> WQKV = WqP [768][256]
  unsigned short* WvP  = WkP + 65536;
  unsigned short* WoP  = WvP + 65536;
  unsigned short* bqP  = (unsigned short*)(ws + 116000000);   // 3 x 256 contiguous = biasAll
  unsigned short* bkP  = bqP + 256;
  unsigned short* bvP  = bkP + 256;
  unsigned short* boC  = bvP + 256;
  int*            flags = (int*)(ws + 116100000);
  unsigned short* Hc   = (unsigned short*)(ws + 117000000);   // 25.6 MB canonical bf16 h

  // dispatch 1: dtype detect (block 0) + cursor zero (blocks 1..63)
  init<<<64, 256, 0, stream>>>((const unsigned short*)h_raw, row_raw, flags, cur);

  // dispatch 2: fused h-conv + weight/bias permute + bucket build
  WPtrs wp;
  wp.srcW[0] = Wq_raw; wp.srcW[1] = Wk_raw; wp.srcW[2] = Wv_raw; wp.srcW[3] = Wo_raw;
  wp.dstW[0] = WqP;    wp.dstW[1] = WkP;    wp.dstW[2] = WvP;    wp.dstW[3] = WoP;
  wp.srcB[0] = bq_raw; wp.srcB[1] = bk_raw; wp.srcB[2] = bv_raw; wp.srcB[3] = bo_raw;
  wp.dstB[0] = bqP;    wp.dstB[1] = bkP;    wp.dstB[2] = bvP;    wp.dstB[3] = boC;
  prep<<<9975, 256, 0, stream>>>(h_raw, Hc, wp, row_raw, col_raw, flags, cur, bkt);

  // dispatch 3: fused QKV GEMM (XCD-swizzled 1D grid, 2-phase dbuf)
  gemm_qkv<<<QKV_NB, 256, 0, stream>>>(Hc, WqP, bqP, Qt, KV, 0.17677669529663687f);

  // dispatches 4+5: fused sparse attention, split into node halves
  // (diagnostic: drops per-dispatch dur to ~58 µs so top-5 reveals the
  // hidden non-attn kernels)
  attn_fused<<<6250, 256, 0, stream>>>(Qt, KV, cur, bkt, pre, 0);
  attn_fused<<<6250, 256, 0, stream>>>(Qt, KV, cur, bkt, pre, 25000);

  // dispatch 6: O-projection (XCD-swizzled 1D grid, 2-phase dbuf)
  gemm_o<<<O_NB, 256, 0, stream>>>(pre, WoP, boC, d_out, flags);
}

// Round 11
// 359.784 us; speedup vs baseline: 1.0684x; 1.0684x over previous
//
#include <hip/hip_runtime.h>
#include <hip/hip_bf16.h>
#include <math.h>

#define N_NODES  50000
#define N_EDGES  800000
#define HIDDEN   256
#define HEADS    8
#define HEAD_DIM 32
#define MAXDEG   64
#define KVSTRIDE 512               // K row | V row interleaved per node
#define QKV_NB   2346              // 391 row-tiles x 6 col-tiles
#define O_NB     782               // 391 row-tiles x 2 col-tiles

// prep grid layout: bucket FIRST (long pole), then h-conv, then weights
#define PREP_BKT   391             // 100000 threads x 8 edges = 800000
#define PREP_HCONV 6400
#define PREP_W     450
#define PREP_NB    (PREP_BKT + PREP_HCONV + PREP_W)   // 7241

using short8 = __attribute__((ext_vector_type(8))) short;
using f32x4  = __attribute__((ext_vector_type(4))) float;

__device__ __forceinline__ float b2f(unsigned short u) {
  union { unsigned int i; float f; } v; v.i = ((unsigned int)u) << 16; return v.f;
}
__device__ __forceinline__ unsigned short f2b(float f) {
  union { float f; unsigned int i; } v; v.f = f;
  unsigned int r = v.i + 0x7FFF + ((v.i >> 16) & 1);   // round-to-nearest-even
  return (unsigned short)(r >> 16);
}
// unpack a dword holding 2 bf16 into 2 floats (1 shl + 1 and)
__device__ __forceinline__ void unpack2(unsigned int d, float& lo, float& hi) {
  union { unsigned int i; float f; } a, b;
  a.i = d << 16; b.i = d & 0xFFFF0000u;
  lo = a.f; hi = b.f;
}

// Bijective XCD-chunked block swizzle (m204 variant).
template<int NB, int NCT>
__device__ __forceinline__ void xcd_map(int b, int& rt, int& ct) {
  constexpr int q = NB / 8, r = NB % 8;
  const int xcd = b & 7, j = b >> 3;
  const int id = (xcd < r ? xcd * (q + 1) : r * (q + 1) + (xcd - r) * q) + j;
  rt = id / NCT; ct = id - rt * NCT;
}

// ---- init: block 0 = dtype detection; other blocks zero the cursor array.
// flags[0]=1 if float tensors are fp32; flags[1]=1 if idx int64
__global__ __launch_bounds__(256) void init(const unsigned short* __restrict__ h16,
                                            const int* __restrict__ rowraw,
                                            int* __restrict__ flags,
                                            int* __restrict__ cur) {
  const int tid = threadIdx.x;
  if (blockIdx.x == 0) {
    __shared__ int nan_cnt, hi_viol, lo_pos;
    if (tid == 0) { nan_cnt = 0; hi_viol = 0; lo_pos = 0; }
    __syncthreads();
    int local = 0;
    for (int i = tid; i < 16384; i += 256)
      if ((h16[i] & 0x7F80) == 0x7F80) local++;   // bf16 NaN/Inf pattern: ~1/256 if fp32
    if (local) atomicAdd(&nan_cnt, local);
    int viol = 0, pos = 0;
    for (int e = tid; e < 512; e += 256) {
      if (rowraw[2 * e + 1] != 0) viol++;
      if (rowraw[2 * e] > 0) pos++;
    }
    if (viol) atomicAdd(&hi_viol, viol);
    if (pos) atomicAdd(&lo_pos, pos);
    __syncthreads();
    if (tid == 0) {
      flags[0] = (nan_cnt >= 4) ? 1 : 0;
      flags[1] = (hi_viol == 0 && lo_pos > 0) ? 1 : 0;
    }
  } else {
    const int i = (blockIdx.x - 1) * 256 + tid;       // 63*256 = 16128 >= 12500
    if (i < N_NODES / 4) ((int4*)cur)[i] = make_int4(0, 0, 0, 0);
  }
}

// Weights + biases pointer pack.
// Wq/Wk/Wv: ROW-permuted (head-major outputs); Wo: K-DIM permuted.
struct WPtrs {
  const void* srcW[4]; unsigned short* dstW[4];
  const void* srcB[4]; unsigned short* dstB[4];
};

// ---- prep: fused bucket build + h-conversion + weight/bias permute.
// Bucket blocks FIRST ([0,391)): they are the latency-bound long pole
// (95 us at 1.9% VALUBusy when 1 edge/thread and dispatched last).
// 8 edges/thread, phase-pipelined: 16 independent loads -> 8 independent
// atomicAdds -> 8 stores. ~8x less latency exposure per thread.
__global__ __launch_bounds__(256) void prep(
    const void* __restrict__ hsrc, unsigned short* __restrict__ Hc, WPtrs p,
    const int* __restrict__ rowraw, const int* __restrict__ colraw,
    const int* __restrict__ flags, int* __restrict__ cursor,
    unsigned short* __restrict__ bucket)
{
  const int fp32 = flags[0];
  const int bid = blockIdx.x, tid = threadIdx.x;

  if (bid < PREP_BKT) {                    // bucket build; ushort cols (N<65536)
    const int t = bid * 256 + tid;
    if (t < N_EDGES / 8) {
      const int i64 = flags[1];
      const int e0 = t * 8;
      int r[8], c[8];
      #pragma unroll
      for (int x = 0; x < 8; ++x) {        // phase 1: independent loads
        const int e = e0 + x;
        r[x] = i64 ? rowraw[2 * e] : rowraw[e];
        c[x] = i64 ? colraw[2 * e] : colraw[e];
      }
      int pos[8];
      #pragma unroll
      for (int x = 0; x < 8; ++x)          // phase 2: independent atomics
        pos[x] = atomicAdd(&cursor[r[x]], 1);
      #pragma unroll
      for (int x = 0; x < 8; ++x)          // phase 3: scattered stores
        if (pos[x] < MAXDEG) bucket[r[x] * MAXDEG + pos[x]] = (unsigned short)c[x];
    }
  } else if (bid < PREP_BKT + PREP_HCONV) {  // canonicalize h -> bf16, vec4
    const int n4 = N_NODES * HIDDEN / 4;
    for (int i = (bid - PREP_BKT) * 256 + tid; i < n4; i += PREP_HCONV * 256) {
      if (fp32) {
        const float4 v = ((const float4*)hsrc)[i];
        ushort4 o; o.x = f2b(v.x); o.y = f2b(v.y); o.z = f2b(v.z); o.w = f2b(v.w);
        ((ushort4*)Hc)[i] = o;
      } else {
        ((ushort4*)Hc)[i] = ((const ushort4*)hsrc)[i];
      }
    }
  } else {                                 // weights + biases
    const int idx = (bid - PREP_BKT - PREP_HCONV) * 256 + tid;
    if (idx < 49152) {                     // Wq,Wk,Wv: vec4 along k, row-permuted
      const int m = idx >> 14, r = idx & 16383;
      const int g = r >> 6, kc = r & 63;
      const int f = ((g & 31) << 3) | (g >> 5);   // source row
      const int s = f * 64 + kc;
      if (fp32) {
        const float4 v = ((const float4*)p.srcW[m])[s];
        ushort4 o; o.x = f2b(v.x); o.y = f2b(v.y); o.z = f2b(v.z); o.w = f2b(v.w);
        ((ushort4*)p.dstW[m])[g * 64 + kc] = o;
      } else {
        ((ushort4*)p.dstW[m])[g * 64 + kc] = ((const ushort4*)p.srcW[m])[s];
      }
    } else if (idx < 49152 + 65536) {      // Wo: scalar, permuted k index
      const int g = idx - 49152;
      const int f = g >> 8, kk = g & 255;
      const int s = f * 256 + (((kk & 31) << 3) | (kk >> 5));
      p.dstW[3][g] = fp32 ? f2b(((const float*)p.srcW[3])[s])
                          : ((const unsigned short*)p.srcW[3])[s];
    } else if (idx < 49152 + 65536 + 256) {  // biases
      const int t = idx - 49152 - 65536;
      const int m = t >> 6, r = t & 63;
      if (m < 3) {
        ushort4 o;
        #pragma unroll
        for (int x = 0; x < 4; ++x) {
          const int g = r * 4 + x;
          const int f = ((g & 31) << 3) | (g >> 5);
          ((unsigned short*)&o)[x] = fp32 ? f2b(((const float*)p.srcB[m])[f])
                                          : ((const unsigned short*)p.srcB[m])[f];
        }
        ((ushort4*)p.dstB[m])[r] = o;
      } else {
        if (fp32) {
          const float4 v = ((const float4*)p.srcB[3])[r];
          ushort4 o; o.x = f2b(v.x); o.y = f2b(v.y); o.z = f2b(v.z); o.w = f2b(v.w);
          ((ushort4*)p.dstB[3])[r] = o;
        } else {
          ((ushort4*)p.dstB[3])[r] = ((const ushort4*)p.srcB[3])[r];
        }
      }
    }
  }
}

// ---- m97-style staging: 128x64 bf16 tile -> LDS [128][64], XOR-swizzled.
#if defined(__has_builtin)
#if __has_builtin(__builtin_amdgcn_global_load_lds)
#define HAVE_GLL 1
#endif
#endif
__device__ __forceinline__ void stage_tile(
    const unsigned short* __restrict__ src, int row_base, int row_max,
    int kb, unsigned short* lds, int wave, int lane)
{
  #pragma unroll
  for (int c = 0; c < 4; ++c) {
    const int chunk = wave * 4 + c;                    // 0..15 (wave-uniform)
    const int r = chunk * 8 + (lane >> 3);             // LDS row 0..127
    int gr = row_base + r; if (gr > row_max) gr = row_max;
    const int scb = (lane & 7) ^ ((lane >> 3) & 7);    // swizzled source col-block
    const unsigned short* gp = src + (size_t)gr * HIDDEN + kb * 64 + scb * 8;
#ifdef HAVE_GLL
    __builtin_amdgcn_global_load_lds(
        (const __attribute__((address_space(1))) void*)gp,
        (__attribute__((address_space(3))) void*)(lds + chunk * 512),
        16, 0, 0);
#else
    *(short8*)(lds + chunk * 512 + lane * 8) = *(const short8*)gp;
#endif
  }
}

// generic 128x128 block-tile MFMA core, DOUBLE-BUFFERED (T3-minimum 2-phase).
#define GEMM_CORE(A_SRC, AROWB, AROWM, B_SRC, BROWB, BROWM)                          \
  __shared__ unsigned short sA[2][8192], sB[2][8192];                                \
  const int wave = threadIdx.x >> 6, lane = threadIdx.x & 63;                        \
  const int lrow = lane & 15, quad = lane >> 4;                                      \
  const int wr0 = (wave & 1) * 64, wc0 = (wave >> 1) * 64;                           \
  f32x4 acc[4][4];                                                                   \
  _Pragma("unroll")                                                                  \
  for (int i = 0; i < 4; ++i)                                                        \
    _Pragma("unroll")                                                                \
    for (int j = 0; j < 4; ++j) acc[i][j] = (f32x4){0.f, 0.f, 0.f, 0.f};            \
  stage_tile(A_SRC, AROWB, AROWM, 0, sA[0], wave, lane);                             \
  stage_tile(B_SRC, BROWB, BROWM, 0, sB[0], wave, lane);                             \
  _Pragma("unroll")                                                                  \
  for (int kb = 0; kb < 4; ++kb) {                                                   \
    __syncthreads();                        /* buf[kb&1] ready; prior reads done */  \
    if (kb < 3) {                                                                    \
      stage_tile(A_SRC, AROWB, AROWM, kb + 1, sA[(kb + 1) & 1], wave, lane);         \
      stage_tile(B_SRC, BROWB, BROWM, kb + 1, sB[(kb + 1) & 1], wave, lane);         \
    }                                                                                \
    const unsigned short* pA = sA[kb & 1];                                           \
    const unsigned short* pB = sB[kb & 1];                                           \
    _Pragma("unroll")                                                                \
    for (int kk = 0; kk < 2; ++kk) {                                                 \
      short8 af[4], bf[4];                                                           \
      _Pragma("unroll")                                                              \
      for (int i = 0; i < 4; ++i) {                                                  \
        const int rr = wr0 + i * 16 + lrow;                                          \
        af[i] = *(const short8*)(pA + rr * 64 + (((kk * 4 + quad) ^ (lrow & 7)) * 8));\
      }                                                                              \
      _Pragma("unroll")                                                              \
      for (int j = 0; j < 4; ++j) {                                                  \
        const int rr = wc0 + j * 16 + lrow;                                          \
        bf[j] = *(const short8*)(pB + rr * 64 + (((kk * 4 + quad) ^ (lrow & 7)) * 8));\
      }                                                                              \
      _Pragma("unroll")                                                              \
      for (int i = 0; i < 4; ++i)                                                    \
        _Pragma("unroll")                                                            \
        for (int j = 0; j < 4; ++j)                                                  \
          acc[i][j] = __builtin_amdgcn_mfma_f32_16x16x32_bf16(af[i], bf[j], acc[i][j], 0, 0, 0); \
    }                                                                                \
  }

// QKV fused: C[50000, 768] = Hc @ WQKV^T (+bias)(*scale for Q cols).
__global__ __launch_bounds__(256) void gemm_qkv(
    const unsigned short* __restrict__ X, const unsigned short* __restrict__ WQKV,
    const unsigned short* __restrict__ biasAll,
    unsigned short* __restrict__ Qt, unsigned short* __restrict__ KV, float qscale)
{
  int rt, ct; xcd_map<QKV_NB, 6>(blockIdx.x, rt, ct);
  const int row0 = rt * 128;
  const int col0 = ct * 128;
  GEMM_CORE(X, row0, N_NODES - 1, WQKV, col0, 767)

  #pragma unroll
  for (int j = 0; j < 4; ++j) {
    const int gcol = col0 + wc0 + j * 16;          // multiple of 16
    const int m = gcol >> 8;
    const int f = (gcol & 255) + lrow;
    const float scale = (m == 0) ? qscale : 1.0f;
    const float bv = b2f(biasAll[gcol + lrow]);
    unsigned short* bp = (m == 0) ? Qt : (KV + ((m == 2) ? 256 : 0));
    const int ldv = (m == 0) ? 256 : KVSTRIDE;
    #pragma unroll
    for (int i = 0; i < 4; ++i) {
      #pragma unroll
      for (int r = 0; r < 4; ++r) {
        const int row = row0 + wr0 + i * 16 + quad * 4 + r;
        if (row < N_NODES)
          bp[(size_t)row * ldv + f] = f2b((acc[i][j][r] + bv) * scale);
      }
    }
  }
}

// O-projection: C[50000, 256] = pre @ WoP^T + bo; out fp32/bf16 per flags[0].
__global__ __launch_bounds__(256) void gemm_o(
    const unsigned short* __restrict__ X, const unsigned short* __restrict__ W,
    const unsigned short* __restrict__ bias, void* __restrict__ Yv,
    const int* __restrict__ flags)
{
  int rt, ct; xcd_map<O_NB, 2>(blockIdx.x, rt, ct);
  const int row0 = rt * 128;
  const int col0 = ct * 128;
  const int out_fp32 = flags[0];
  GEMM_CORE(X, row0, N_NODES - 1, W, col0, 255)

  #pragma unroll
  for (int j = 0; j < 4; ++j) {
    const int col = col0 + wc0 + j * 16 + lrow;
    const float bv = b2f(bias[col]);
    #pragma unroll
    for (int i = 0; i < 4; ++i) {
      #pragma unroll
      for (int r = 0; r < 4; ++r) {
        const int row = row0 + wr0 + i * 16 + quad * 4 + r;
        if (row < N_NODES) {
          const float y = acc[i][j][r] + bv;
          if (out_fp32) ((float*)Yv)[(size_t)row * HIDDEN + col] = y;
          else ((unsigned short*)Yv)[(size_t)row * HIDDEN + col] = f2b(y);
        }
      }
    }
  }
}

// Fused SDDMM + exp + SPMM — frozen at the gather-path roofline
// (~386 MB compulsory cross-XCD L2-fill @ ~3.65 TB/s; four schedule
// variants all pinned at 115.5±1 µs). Single dispatch restored.
__global__ __launch_bounds__(256) void attn_fused(
    const unsigned short* __restrict__ Qt, const unsigned short* __restrict__ KV,
    const int* __restrict__ cursor, const unsigned short* __restrict__ bucket,
    unsigned short* __restrict__ pre)
{
  const int node = blockIdx.x * 4 + (threadIdx.x >> 6);
  if (node >= N_NODES) return;
  const int lane = threadIdx.x & 63;
  const int side = lane >> 5;          // which edge of the current pair
  const int sub  = lane & 31;          // owns cols [8*sub, 8*sub+8)
  const unsigned suboff = (unsigned)(sub * 8);
  int cnt = cursor[node]; if (cnt > MAXDEG) cnt = MAXDEG;

  // Q: 8 floats (scale already folded in by gemm_qkv); both halves read same row
  const uint4 qd = *(const uint4*)(Qt + (unsigned)node * HIDDEN + suboff);
  float q[8];
  unpack2(qd.x, q[0], q[1]); unpack2(qd.y, q[2], q[3]);
  unpack2(qd.z, q[4], q[5]); unpack2(qd.w, q[6], q[7]);

  float a[8] = {0.f, 0.f, 0.f, 0.f, 0.f, 0.f, 0.f, 0.f};
  float z = 0.f;

  if (cnt > 0) {
    const int last = cnt - 1;
    const unsigned short* brow = bucket + node * MAXDEG;
    // clamped per-lane edge index: any shuffle source yields a valid col
    const int myidx = (int)brow[lane <= last ? lane : last];
    const int nit = (cnt + 1) >> 1;

    auto compute = [&](const uint4& kk, const uint4& vv, int jj) {
      float kf[8];
      unpack2(kk.x, kf[0], kf[1]); unpack2(kk.y, kf[2], kf[3]);
      unpack2(kk.z, kf[4], kf[5]); unpack2(kk.w, kf[6], kf[7]);
      float s0 = q[0]*kf[0] + q[2]*kf[2] + q[4]*kf[4] + q[6]*kf[6];
      float s1 = q[1]*kf[1] + q[3]*kf[3] + q[5]*kf[5] + q[7]*kf[7];
      float d = s0 + s1;
      d += __shfl_xor(d, 1, 64);       // 4-lane (one head) reduce: 2 rounds
      d += __shfl_xor(d, 2, 64);
      float w = __expf(d);
      if (2 * jj + side > last) w = 0.f;   // mask odd tail / clamped dup
      z += w;
      float vf[8];
      unpack2(vv.x, vf[0], vf[1]); unpack2(vv.y, vf[2], vf[3]);
      unpack2(vv.z, vf[4], vf[5]); unpack2(vv.w, vf[6], vf[7]);
      #pragma unroll
      for (int x = 0; x < 8; ++x) a[x] = fmaf(w, vf[x], a[x]);
    };

    // ---- prologue: pairs 0 and 1 in flight (clamped idx safe, masked later)
    const int cA = __shfl(myidx, side, 64);
    const unsigned offA = ((unsigned)cA << 9) + suboff;
    uint4 kA = *(const uint4*)(KV + offA);
    uint4 vA = *(const uint4*)(KV + offA + 256u);

    const int cB = __shfl(myidx, 2 + side, 64);      // lane 2/3: always valid
    const unsigned offB = ((unsigned)cB << 9) + suboff;
    uint4 kB = *(const uint4*)(KV + offB);
    uint4 vB = *(const uint4*)(KV + offB + 256u);

    int slC = 4 + side;                              // pair-2 source lane
    int cC = __shfl(myidx, slC, 64);

    int j = 0;
    #pragma unroll 2
    for (; j + 2 < nit; ++j) {
      const unsigned offC = ((unsigned)cC << 9) + suboff;
      const uint4 kC = *(const uint4*)(KV + offC);
      const uint4 vC = *(const uint4*)(KV + offC + 256u);
      int sl = 2 * (j + 3) + side; if (sl > 63) sl = 63;
      cC = __shfl(myidx, sl, 64);
      compute(kA, vA, j);
      kA = kB; vA = vB; kB = kC; vB = vC;
    }
    compute(kA, vA, j);                 // pair nit-2 (or nit-1 if nit==1)
    if (j + 1 < nit) compute(kB, vB, j + 1);   // pair nit-1
  }

  // cross-half combine (once per node)
  #pragma unroll
  for (int x = 0; x < 8; ++x) a[x] += __shfl_xor(a[x], 32, 64);
  z += __shfl_xor(z, 32, 64);
  const float zi = (z > 0.f) ? (1.f / z) : 0.f;

  if (side == 0) {
    short8 ov;
    #pragma unroll
    for (int x = 0; x < 8; ++x) ov[x] = (short)f2b(a[x] * zi);
    *(short8*)(pre + (unsigned)node * HIDDEN + suboff) = ov;
  }
}

extern "C" void kernel_launch(void* const* d_in, const int* in_sizes, int n_in,
                              void* d_out, int out_size, void* d_ws, size_t ws_size,
                              hipStream_t stream) {
  const void* h_raw  = d_in[0];
  const int* row_raw = (const int*)d_in[1];
  const int* col_raw = (const int*)d_in[2];
  const void* Wq_raw = d_in[3]; const void* bq_raw = d_in[4];
  const void* Wk_raw = d_in[5]; const void* bk_raw = d_in[6];
  const void* Wv_raw = d_in[7]; const void* bv_raw = d_in[8];
  const void* Wo_raw = d_in[9]; const void* bo_raw = d_in[10];

  char* ws = (char*)d_ws;
  unsigned short* Qt   = (unsigned short*)(ws +          0);  // 25.6 MB
  unsigned short* KV   = (unsigned short*)(ws +  25600000);   // 51.2 MB interleaved K|V
  int*            cur  = (int*)           (ws +  76800000);   // 0.2 MB
  unsigned short* bkt  = (unsigned short*)(ws +  77000000);   // 6.4 MB (ushort cols)
  unsigned short* pre  = (unsigned short*)(ws +  89800000);   // 25.6 MB
  unsigned short* WqP  = (unsigned short*)(ws + 115400000);   // 4 x 128 KB, contiguous
  unsigned short* WkP  = WqP + 65536;                         //  -> WQKV = WqP [768][256]
  unsigned short* WvP  = WkP + 65536;
  unsigned short* WoP  = WvP + 65536;
  unsigned short* bqP  = (unsigned short*)(ws + 116000000);   // 3 x 256 contiguous = biasAll
  unsigned short* bkP  = bqP + 256;
  unsigned short* bvP  = bkP + 256;
  unsigned short* boC  = bvP + 256;
  int*            flags = (int*)(ws + 116100000);
  unsigned short* Hc   = (unsigned short*)(ws + 117000000);   // 25.6 MB canonical bf16 h

  // dispatch 1: dtype detect (block 0) + cursor zero (blocks 1..63)
  init<<<64, 256, 0, stream>>>((const unsigned short*)h_raw, row_raw, flags, cur);

  // dispatch 2: fused bucket build (first) + h-conv + weight/bias permute
  WPtrs wp;
  wp.srcW[0] = Wq_raw; wp.srcW[1] = Wk_raw; wp.srcW[2] = Wv_raw; wp.srcW[3] = Wo_raw;
  wp.dstW[0] = WqP;    wp.dstW[1] = WkP;    wp.dstW[2] = WvP;    wp.dstW[3] = WoP;
  wp.srcB[0] = bq_raw; wp.srcB[1] = bk_raw; wp.srcB[2] = bv_raw; wp.srcB[3] = bo_raw;
  wp.dstB[0] = bqP;    wp.dstB[1] = bkP;    wp.dstB[2] = bvP;    wp.dstB[3] = boC;
  prep<<<PREP_NB, 256, 0, stream>>>(h_raw, Hc, wp, row_raw, col_raw, flags, cur, bkt);

  // dispatch 3: fused QKV GEMM (XCD-swizzled 1D grid, 2-phase dbuf)
  gemm_qkv<<<QKV_NB, 256, 0, stream>>>(Hc, WqP, bqP, Qt, KV, 0.17677669529663687f);

  // dispatch 4: fused sparse attention
  attn_fused<<<(N_NODES + 3) / 4, 256, 0, stream>>>(Qt, KV, cur, bkt, pre);

  // dispatch 5: O-projection (XCD-swizzled 1D grid, 2-phase dbuf)
  gemm_o<<<O_NB, 256, 0, stream>>>(pre, WoP, boC, d_out, flags);
}

// Round 15
// 347.228 us; speedup vs baseline: 1.1070x; 1.0362x over previous
//
#include <hip/hip_runtime.h>
#include <hip/hip_bf16.h>
#include <math.h>

#define N_NODES  50000
#define N_EDGES  800000
#define HIDDEN   256
#define HEADS    8
#define HEAD_DIM 32
#define MAXDEG   64
#define KVSTRIDE 512               // K row | V row interleaved per node
#define QKV_NB   2346              // 391 row-tiles x 6 col-tiles
#define O_NB     782               // 391 row-tiles x 2 col-tiles
#define BKT_NB   391               // 100096 threads x 8 edges >= 800000
#define QKVB_NB  (QKV_NB + BKT_NB) // 2737 = 7 * 391: every 7th block = bucket
#define PREP_HCONV 6400
#define PREP_NB  (PREP_HCONV + 450)

using short8 = __attribute__((ext_vector_type(8))) short;
using f32x4  = __attribute__((ext_vector_type(4))) float;

__device__ __forceinline__ float b2f(unsigned short u) {
  union { unsigned int i; float f; } v; v.i = ((unsigned int)u) << 16; return v.f;
}
__device__ __forceinline__ unsigned short f2b(float f) {
  union { float f; unsigned int i; } v; v.f = f;
  unsigned int r = v.i + 0x7FFF + ((v.i >> 16) & 1);   // round-to-nearest-even
  return (unsigned short)(r >> 16);
}
// unpack a dword holding 2 bf16 into 2 floats (1 shl + 1 and)
__device__ __forceinline__ void unpack2(unsigned int d, float& lo, float& hi) {
  union { unsigned int i; float f; } a, b;
  a.i = d << 16; b.i = d & 0xFFFF0000u;
  lo = a.f; hi = b.f;
}

// dtype flags derived from cnt[3] (written by init's distributed scan):
// cnt[0]=bf16-NaN-pattern hits in h's first 16384 u16 (>=4 -> h is fp32)
// cnt[1]=nonzero high words in row[0:512] (0 -> plausibly int64)
// cnt[2]=positive low words (>0 -> confirms int64 when cnt[1]==0)
__device__ __forceinline__ int flag_fp32(const int* cnt) { return cnt[0] >= 4; }
__device__ __forceinline__ int flag_i64 (const int* cnt) { return cnt[1] == 0 && cnt[2] > 0; }

// Bijective XCD-chunked block swizzle (m204 variant).
template<int NB, int NCT>
__device__ __forceinline__ void xcd_map(int b, int& rt, int& ct) {
  constexpr int q = NB / 8, r = NB % 8;
  const int xcd = b & 7, j = b >> 3;
  const int id = (xcd < r ? xcd * (q + 1) : r * (q + 1) + (xcd - r) * q) + j;
  rt = id / NCT; ct = id - rt * NCT;
}

// ---- init: distributed dtype scan (1 h-element/thread across 64 blocks,
// wave-aggregated atomics) + rowraw check (block 0) + cursor zeroing.
__global__ __launch_bounds__(256) void init(const unsigned short* __restrict__ h16,
                                            const int* __restrict__ rowraw,
                                            int* __restrict__ cnt,
                                            int* __restrict__ cur) {
  const int tid = threadIdx.x, bid = blockIdx.x;
  const int i = bid * 256 + tid;               // 64*256 = 16384 exactly
  const int isnan16 = (h16[i] & 0x7F80) == 0x7F80;
  const unsigned long long m = __ballot(isnan16);
  if ((tid & 63) == 0 && m) atomicAdd(&cnt[0], __popcll(m));

  if (bid == 0) {
    int viol = 0, pos = 0;
    for (int e = tid; e < 512; e += 256) {
      if (rowraw[2 * e + 1] != 0) viol++;
      if (rowraw[2 * e] > 0) pos++;
    }
    if (viol) atomicAdd(&cnt[1], viol);
    if (pos) atomicAdd(&cnt[2], pos);
  } else {
    const int j = (bid - 1) * 256 + tid;       // 63*256 = 16128 >= 12500
    if (j < N_NODES / 4) ((int4*)cur)[j] = make_int4(0, 0, 0, 0);
  }
}

// Weights + biases pointer pack.
// Wq/Wk/Wv: ROW-permuted (head-major outputs); Wo: K-DIM permuted.
struct WPtrs {
  const void* srcW[4]; unsigned short* dstW[4];
  const void* srcB[4]; unsigned short* dstB[4];
};

// ---- prep: h-conversion + weight/bias permute-convert ONLY.
// (bucket build moved into gemm_qkv's grid — it is fabric/latency-bound,
// not BW-bound, so it hides under the compute-bound GEMM.)
__global__ __launch_bounds__(256) void prep(
    const void* __restrict__ hsrc, unsigned short* __restrict__ Hc, WPtrs p,
    const int* __restrict__ cnt)
{
  const int fp32 = flag_fp32(cnt);
  const int bid = blockIdx.x, tid = threadIdx.x;

  if (bid < PREP_HCONV) {                  // canonicalize h -> bf16, vec4
    const int n4 = N_NODES * HIDDEN / 4;
    for (int i = bid * 256 + tid; i < n4; i += PREP_HCONV * 256) {
      if (fp32) {
        const float4 v = ((const float4*)hsrc)[i];
        ushort4 o; o.x = f2b(v.x); o.y = f2b(v.y); o.z = f2b(v.z); o.w = f2b(v.w);
        ((ushort4*)Hc)[i] = o;
      } else {
        ((ushort4*)Hc)[i] = ((const ushort4*)hsrc)[i];
      }
    }
  } else {                                 // weights + biases
    const int idx = (bid - PREP_HCONV) * 256 + tid;
    if (idx < 49152) {                     // Wq,Wk,Wv: vec4 along k, row-permuted
      const int m = idx >> 14, r = idx & 16383;
      const int g = r >> 6, kc = r & 63;
      const int f = ((g & 31) << 3) | (g >> 5);   // source row
      const int s = f * 64 + kc;
      if (fp32) {
        const float4 v = ((const float4*)p.srcW[m])[s];
        ushort4 o; o.x = f2b(v.x); o.y = f2b(v.y); o.z = f2b(v.z); o.w = f2b(v.w);
        ((ushort4*)p.dstW[m])[g * 64 + kc] = o;
      } else {
        ((ushort4*)p.dstW[m])[g * 64 + kc] = ((const ushort4*)p.srcW[m])[s];
      }
    } else if (idx < 49152 + 65536) {      // Wo: scalar, permuted k index
      const int g = idx - 49152;
      const int f = g >> 8, kk = g & 255;
      const int s = f * 256 + (((kk & 31) << 3) | (kk >> 5));
      p.dstW[3][g] = fp32 ? f2b(((const float*)p.srcW[3])[s])
                          : ((const unsigned short*)p.srcW[3])[s];
    } else if (idx < 49152 + 65536 + 256) {  // biases
      const int t = idx - 49152 - 65536;
      const int m = t >> 6, r = t & 63;
      if (m < 3) {
        ushort4 o;
        #pragma unroll
        for (int x = 0; x < 4; ++x) {
          const int g = r * 4 + x;
          const int f = ((g & 31) << 3) | (g >> 5);
          ((unsigned short*)&o)[x] = fp32 ? f2b(((const float*)p.srcB[m])[f])
                                          : ((const unsigned short*)p.srcB[m])[f];
        }
        ((ushort4*)p.dstB[m])[r] = o;
      } else {
        if (fp32) {
          const float4 v = ((const float4*)p.srcB[3])[r];
          ushort4 o; o.x = f2b(v.x); o.y = f2b(v.y); o.z = f2b(v.z); o.w = f2b(v.w);
          ((ushort4*)p.dstB[3])[r] = o;
        } else {
          ((ushort4*)p.dstB[3])[r] = ((const ushort4*)p.srcB[3])[r];
        }
      }
    }
  }
}

// ---- m97-style staging: 128x64 bf16 tile -> LDS [128][64], XOR-swizzled.
#if defined(__has_builtin)
#if __has_builtin(__builtin_amdgcn_global_load_lds)
#define HAVE_GLL 1
#endif
#endif
__device__ __forceinline__ void stage_tile(
    const unsigned short* __restrict__ src, int row_base, int row_max,
    int kb, unsigned short* lds, int wave, int lane)
{
  #pragma unroll
  for (int c = 0; c < 4; ++c) {
    const int chunk = wave * 4 + c;                    // 0..15 (wave-uniform)
    const int r = chunk * 8 + (lane >> 3);             // LDS row 0..127
    int gr = row_base + r; if (gr > row_max) gr = row_max;
    const int scb = (lane & 7) ^ ((lane >> 3) & 7);    // swizzled source col-block
    const unsigned short* gp = src + (size_t)gr * HIDDEN + kb * 64 + scb * 8;
#ifdef HAVE_GLL
    __builtin_amdgcn_global_load_lds(
        (const __attribute__((address_space(1))) void*)gp,
        (__attribute__((address_space(3))) void*)(lds + chunk * 512),
        16, 0, 0);
#else
    *(short8*)(lds + chunk * 512 + lane * 8) = *(const short8*)gp;
#endif
  }
}

// generic 128x128 block-tile MFMA core, DOUBLE-BUFFERED (T3-minimum 2-phase).
#define GEMM_CORE(A_SRC, AROWB, AROWM, B_SRC, BROWB, BROWM)                          \
  __shared__ unsigned short sA[2][8192], sB[2][8192];                                \
  const int wave = threadIdx.x >> 6, lane = threadIdx.x & 63;                        \
  const int lrow = lane & 15, quad = lane >> 4;                                      \
  const int wr0 = (wave & 1) * 64, wc0 = (wave >> 1) * 64;                           \
  f32x4 acc[4][4];                                                                   \
  _Pragma("unroll")                                                                  \
  for (int i = 0; i < 4; ++i)                                                        \
    _Pragma("unroll")                                                                \
    for (int j = 0; j < 4; ++j) acc[i][j] = (f32x4){0.f, 0.f, 0.f, 0.f};            \
  stage_tile(A_SRC, AROWB, AROWM, 0, sA[0], wave, lane);                             \
  stage_tile(B_SRC, BROWB, BROWM, 0, sB[0], wave, lane);                             \
  _Pragma("unroll")                                                                  \
  for (int kb = 0; kb < 4; ++kb) {                                                   \
    __syncthreads();                        /* buf[kb&1] ready; prior reads done */  \
    if (kb < 3) {                                                                    \
      stage_tile(A_SRC, AROWB, AROWM, kb + 1, sA[(kb + 1) & 1], wave, lane);         \
      stage_tile(B_SRC, BROWB, BROWM, kb + 1, sB[(kb + 1) & 1], wave, lane);         \
    }                                                                                \
    const unsigned short* pA = sA[kb & 1];                                           \
    const unsigned short* pB = sB[kb & 1];                                           \
    _Pragma("unroll")                                                                \
    for (int kk = 0; kk < 2; ++kk) {                                                 \
      short8 af[4], bf[4];                                                           \
      _Pragma("unroll")                                                              \
      for (int i = 0; i < 4; ++i) {                                                  \
        const int rr = wr0 + i * 16 + lrow;                                          \
        af[i] = *(const short8*)(pA + rr * 64 + (((kk * 4 + quad) ^ (lrow & 7)) * 8));\
      }                                                                              \
      _Pragma("unroll")                                                              \
      for (int j = 0; j < 4; ++j) {                                                  \
        const int rr = wc0 + j * 16 + lrow;                                          \
        bf[j] = *(const short8*)(pB + rr * 64 + (((kk * 4 + quad) ^ (lrow & 7)) * 8));\
      }                                                                              \
      _Pragma("unroll")                                                              \
      for (int i = 0; i < 4; ++i)                                                    \
        _Pragma("unroll")                                                            \
        for (int j = 0; j < 4; ++j)                                                  \
          acc[i][j] = __builtin_amdgcn_mfma_f32_16x16x32_bf16(af[i], bf[j], acc[i][j], 0, 0, 0); \
    }                                                                                \
  }

// QKV fused GEMM + interleaved bucket-build blocks.
// Grid = 2737 = 7*391: blockIdx%7==6 -> bucket block (391 of them, spread
// through the dispatch order so their fabric-bound atomics/stores overlap
// the compute-bound GEMM without starving it); else GEMM block.
__global__ __launch_bounds__(256) void gemm_qkv(
    const unsigned short* __restrict__ X, const unsigned short* __restrict__ WQKV,
    const unsigned short* __restrict__ biasAll,
    unsigned short* __restrict__ Qt, unsigned short* __restrict__ KV, float qscale,
    const int* __restrict__ rowraw, const int* __restrict__ colraw,
    const int* __restrict__ cnt, int* __restrict__ cursor,
    unsigned short* __restrict__ bucket)
{
  const int b = blockIdx.x;
  if (b % 7 == 6) {                        // ---- bucket build; ushort cols
    const int t = (b / 7) * 256 + threadIdx.x;
    if (t < N_EDGES / 8) {
      const int i64 = flag_i64(cnt);
      const int e0 = t * 8;
      int r[8], c[8];
      #pragma unroll
      for (int x = 0; x < 8; ++x) {        // phase 1: independent loads
        const int e = e0 + x;
        r[x] = i64 ? rowraw[2 * e] : rowraw[e];
        c[x] = i64 ? colraw[2 * e] : colraw[e];
      }
      int pos[8];
      #pragma unroll
      for (int x = 0; x < 8; ++x)          // phase 2: independent atomics
        pos[x] = atomicAdd(&cursor[r[x]], 1);
      #pragma unroll
      for (int x = 0; x < 8; ++x)          // phase 3: scattered stores
        if (pos[x] < MAXDEG) bucket[r[x] * MAXDEG + pos[x]] = (unsigned short)c[x];
    }
    return;
  }
  const int gid = b - (b + 1) / 7;         // 0..QKV_NB-1 over non-bucket blocks
  int rt, ct; xcd_map<QKV_NB, 6>(gid, rt, ct);
  const int row0 = rt * 128;
  const int col0 = ct * 128;
  GEMM_CORE(X, row0, N_NODES - 1, WQKV, col0, 767)

  #pragma unroll
  for (int j = 0; j < 4; ++j) {
    const int gcol = col0 + wc0 + j * 16;          // multiple of 16
    const int m = gcol >> 8;
    const int f = (gcol & 255) + lrow;
    const float scale = (m == 0) ? qscale : 1.0f;
    const float bv = b2f(biasAll[gcol + lrow]);
    unsigned short* bp = (m == 0) ? Qt : (KV + ((m == 2) ? 256 : 0));
    const int ldv = (m == 0) ? 256 : KVSTRIDE;
    #pragma unroll
    for (int i = 0; i < 4; ++i) {
      #pragma unroll
      for (int r = 0; r < 4; ++r) {
        const int row = row0 + wr0 + i * 16 + quad * 4 + r;
        if (row < N_NODES)
          bp[(size_t)row * ldv + f] = f2b((acc[i][j][r] + bv) * scale);
      }
    }
  }
}

// O-projection: C[50000, 256] = pre @ WoP^T + bo; out fp32/bf16 per dtype.
__global__ __launch_bounds__(256) void gemm_o(
    const unsigned short* __restrict__ X, const unsigned short* __restrict__ W,
    const unsigned short* __restrict__ bias, void* __restrict__ Yv,
    const int* __restrict__ cnt)
{
  int rt, ct; xcd_map<O_NB, 2>(blockIdx.x, rt, ct);
  const int row0 = rt * 128;
  const int col0 = ct * 128;
  const int out_fp32 = flag_fp32(cnt);
  GEMM_CORE(X, row0, N_NODES - 1, W, col0, 255)

  #pragma unroll
  for (int j = 0; j < 4; ++j) {
    const int col = col0 + wc0 + j * 16 + lrow;
    const float bv = b2f(bias[col]);
    #pragma unroll
    for (int i = 0; i < 4; ++i) {
      #pragma unroll
      for (int r = 0; r < 4; ++r) {
        const int row = row0 + wr0 + i * 16 + quad * 4 + r;
        if (row < N_NODES) {
          const float y = acc[i][j][r] + bv;
          if (out_fp32) ((float*)Yv)[(size_t)row * HIDDEN + col] = y;
          else ((unsigned short*)Yv)[(size_t)row * HIDDEN + col] = f2b(y);
        }
      }
    }
  }
}

// Fused SDDMM + exp + SPMM — frozen at the gather-path roofline
// (~386 MB compulsory cross-XCD L2-fill @ ~3.65 TB/s; four schedule
// variants all pinned at 115.5±1 µs).
__global__ __launch_bounds__(256) void attn_fused(
    const unsigned short* __restrict__ Qt, const unsigned short* __restrict__ KV,
    const int* __restrict__ cursor, const unsigned short* __restrict__ bucket,
    unsigned short* __restrict__ pre)
{
  const int node = blockIdx.x * 4 + (threadIdx.x >> 6);
  if (node >= N_NODES) return;
  const int lane = threadIdx.x & 63;
  const int side = lane >> 5;          // which edge of the current pair
  const int sub  = lane & 31;          // owns cols [8*sub, 8*sub+8)
  const unsigned suboff = (unsigned)(sub * 8);
  int cnt = cursor[node]; if (cnt > MAXDEG) cnt = MAXDEG;

  // Q: 8 floats (scale already folded in by gemm_qkv); both halves read same row
  const uint4 qd = *(const uint4*)(Qt + (unsigned)node * HIDDEN + suboff);
  float q[8];
  unpack2(qd.x, q[0], q[1]); unpack2(qd.y, q[2], q[3]);
  unpack2(qd.z, q[4], q[5]); unpack2(qd.w, q[6], q[7]);

  float a[8] = {0.f, 0.f, 0.f, 0.f, 0.f, 0.f, 0.f, 0.f};
  float z = 0.f;

  if (cnt > 0) {
    const int last = cnt - 1;
    const unsigned short* brow = bucket + node * MAXDEG;
    // clamped per-lane edge index: any shuffle source yields a valid col
    const int myidx = (int)brow[lane <= last ? lane : last];
    const int nit = (cnt + 1) >> 1;

    auto compute = [&](const uint4& kk, const uint4& vv, int jj) {
      float kf[8];
      unpack2(kk.x, kf[0], kf[1]); unpack2(kk.y, kf[2], kf[3]);
      unpack2(kk.z, kf[4], kf[5]); unpack2(kk.w, kf[6], kf[7]);
      float s0 = q[0]*kf[0] + q[2]*kf[2] + q[4]*kf[4] + q[6]*kf[6];
      float s1 = q[1]*kf[1] + q[3]*kf[3] + q[5]*kf[5] + q[7]*kf[7];
      float d = s0 + s1;
      d += __shfl_xor(d, 1, 64);       // 4-lane (one head) reduce: 2 rounds
      d += __shfl_xor(d, 2, 64);
      float w = __expf(d);
      if (2 * jj + side > last) w = 0.f;   // mask odd tail / clamped dup
      z += w;
      float vf[8];
      unpack2(vv.x, vf[0], vf[1]); unpack2(vv.y, vf[2], vf[3]);
      unpack2(vv.z, vf[4], vf[5]); unpack2(vv.w, vf[6], vf[7]);
      #pragma unroll
      for (int x = 0; x < 8; ++x) a[x] = fmaf(w, vf[x], a[x]);
    };

    // ---- prologue: pairs 0 and 1 in flight (clamped idx safe, masked later)
    const int cA = __shfl(myidx, side, 64);
    const unsigned offA = ((unsigned)cA << 9) + suboff;
    uint4 kA = *(const uint4*)(KV + offA);
    uint4 vA = *(const uint4*)(KV + offA + 256u);

    const int cB = __shfl(myidx, 2 + side, 64);      // lane 2/3: always valid
    const unsigned offB = ((unsigned)cB << 9) + suboff;
    uint4 kB = *(const uint4*)(KV + offB);
    uint4 vB = *(const uint4*)(KV + offB + 256u);

    int slC = 4 + side;                              // pair-2 source lane
    int cC = __shfl(myidx, slC, 64);

    int j = 0;
    #pragma unroll 2
    for (; j + 2 < nit; ++j) {
      const unsigned offC = ((unsigned)cC << 9) + suboff;
      const uint4 kC = *(const uint4*)(KV + offC);
      const uint4 vC = *(const uint4*)(KV + offC + 256u);
      int sl = 2 * (j + 3) + side; if (sl > 63) sl = 63;
      cC = __shfl(myidx, sl, 64);
      compute(kA, vA, j);
      kA = kB; vA = vB; kB = kC; vB = vC;
    }
    compute(kA, vA, j);                 // pair nit-2 (or nit-1 if nit==1)
    if (j + 1 < nit) compute(kB, vB, j + 1);   // pair nit-1
  }

  // cross-half combine (once per node)
  #pragma unroll
  for (int x = 0; x < 8; ++x) a[x] += __shfl_xor(a[x], 32, 64);
  z += __shfl_xor(z, 32, 64);
  const float zi = (z > 0.f) ? (1.f / z) : 0.f;

  if (side == 0) {
    short8 ov;
    #pragma unroll
    for (int x = 0; x < 8; ++x) ov[x] = (short)f2b(a[x] * zi);
    *(short8*)(pre + (unsigned)node * HIDDEN + suboff) = ov;
  }
}

extern "C" void kernel_launch(void* const* d_in, const int* in_sizes, int n_in,
                              void* d_out, int out_size, void* d_ws, size_t ws_size,
                              hipStream_t stream) {
  const void* h_raw  = d_in[0];
  const int* row_raw = (const int*)d_in[1];
  const int* col_raw = (const int*)d_in[2];
  const void* Wq_raw = d_in[3]; const void* bq_raw = d_in[4];
  const void* Wk_raw = d_in[5]; const void* bk_raw = d_in[6];
  const void* Wv_raw = d_in[7]; const void* bv_raw = d_in[8];
  const void* Wo_raw = d_in[9]; const void* bo_raw = d_in[10];

  char* ws = (char*)d_ws;
  unsigned short* Qt   = (unsigned short*)(ws +          0);  // 25.6 MB
  unsigned short* KV   = (unsigned short*)(ws +  25600000);   // 51.2 MB interleaved K|V
  int*            cur  = (int*)           (ws +  76800000);   // 0.2 MB
  unsigned short* bkt  = (unsigned short*)(ws +  77000000);   // 6.4 MB (ushort cols)
  unsigned short* pre  = (unsigned short*)(ws +  89800000);   // 25.6 MB
  unsigned short* WqP  = (unsigned short*)(ws + 115400000);   // 4 x 128 KB, contiguous
  unsigned short* WkP  = WqP + 65536;                         //  -> WQKV = WqP [768][256]
  unsigned short* WvP  = WkP + 65536;
  unsigned short* WoP  = WvP + 65536;
  unsigned short* bqP  = (unsigned short*)(ws + 116000000);   // 3 x 256 contiguous = biasAll
  unsigned short* bkP  = bqP + 256;
  unsigned short* bvP  = bkP + 256;
  unsigned short* boC  = bvP + 256;
  int*            cnt  = (int*)(ws + 116100000);              // 3 dtype-scan counters
  unsigned short* Hc   = (unsigned short*)(ws + 117000000);   // 25.6 MB canonical bf16 h

  // zero the dtype counters, then distributed detect + cursor zero
  hipMemsetAsync(cnt, 0, 16, stream);
  init<<<64, 256, 0, stream>>>((const unsigned short*)h_raw, row_raw, cnt, cur);

  // h-conv + weight/bias permute (bucket build moved into gemm_qkv)
  WPtrs wp;
  wp.srcW[0] = Wq_raw; wp.srcW[1] = Wk_raw; wp.srcW[2] = Wv_raw; wp.srcW[3] = Wo_raw;
  wp.dstW[0] = WqP;    wp.dstW[1] = WkP;    wp.dstW[2] = WvP;    wp.dstW[3] = WoP;
  wp.srcB[0] = bq_raw; wp.srcB[1] = bk_raw; wp.srcB[2] = bv_raw; wp.srcB[3] = bo_raw;
  wp.dstB[0] = bqP;    wp.dstB[1] = bkP;    wp.dstB[2] = bvP;    wp.dstB[3] = boC;
  prep<<<PREP_NB, 256, 0, stream>>>(h_raw, Hc, wp, cnt);

  // fused QKV GEMM with interleaved bucket-build blocks (1 per 6 GEMM blocks)
  gemm_qkv<<<QKVB_NB, 256, 0, stream>>>(Hc, WqP, bqP, Qt, KV, 0.17677669529663687f,
                                        row_raw, col_raw, cnt, cur, bkt);

  // fused sparse attention
  attn_fused<<<(N_NODES + 3) / 4, 256, 0, stream>>>(Qt, KV, cur, bkt, pre);

  // O-projection
  gemm_o<<<O_NB, 256, 0, stream>>>(pre, WoP, boC, d_out, cnt);
}